// Round 13
// baseline (130.572 us; speedup 1.0000x reference)
//
#include <hip/hip_runtime.h>
#include <cstdint>
#include <cstddef>

typedef __bf16 bf16x8 __attribute__((ext_vector_type(8)));
typedef __bf16 bf16x2 __attribute__((ext_vector_type(2)));
typedef float f32x16 __attribute__((ext_vector_type(16)));
typedef unsigned short u16x2 __attribute__((ext_vector_type(2)));

constexpr int HH = 1024;   // hidden dim
constexpr int II = 1024;   // intermediate dim
constexpr int KMAX = 2;
constexpr int EMAX = 8;
constexpr int GU_TILES = 24;   // M=128 tiles: worst case 16 + 8
constexpr int DN_TILES = 40;   // M=64 tiles: worst case 32 + 8
constexpr float FALPHA = 1.702f;
constexpr float FLIMIT = 7.0f;

#if __has_builtin(__builtin_amdgcn_cvt_scalef32_pk_bf16_fp4)
#define USE_CVT 1
#else
#define USE_CVT 0
#endif

#define SCHED0() __builtin_amdgcn_sched_barrier(0)

// ---- fallback perm decode (k-order within 8-group permuted [0,2,4,6,1,3,5,7]) ----
__device__ __forceinline__ unsigned pk_add16(unsigned a, unsigned b) {
  u16x2 x, y;
  __builtin_memcpy(&x, &a, 4); __builtin_memcpy(&y, &b, 4);
  u16x2 r = x + y;
  unsigned o; __builtin_memcpy(&o, &r, 4); return o;
}
__device__ __forceinline__ int4 decode_chunk(int4 raw, unsigned addk) {
  unsigned p = (unsigned)raw.x | ((unsigned)raw.y << 8) |
               ((unsigned)raw.z << 16) | ((unsigned)raw.w << 24);
  unsigned q = p >> 4;
  unsigned me = p & 0x07070707u, mo = q & 0x07070707u;
  unsigned se = p & 0x08080808u, so = q & 0x08080808u;
  unsigned hiE = __builtin_amdgcn_perm(0x40404040u, 0x3F3F3F14u, me) | (se << 4);
  unsigned hiO = __builtin_amdgcn_perm(0x40404040u, 0x3F3F3F14u, mo) | (so << 4);
  unsigned loE = __builtin_amdgcn_perm(0xC0804000u, 0xC0800000u, me);
  unsigned loO = __builtin_amdgcn_perm(0xC0804000u, 0xC0800000u, mo);
  int4 out;
  out.x = (int)pk_add16(__builtin_amdgcn_perm(hiE, loE, 0x05010400u), addk);
  out.y = (int)pk_add16(__builtin_amdgcn_perm(hiE, loE, 0x07030602u), addk);
  out.z = (int)pk_add16(__builtin_amdgcn_perm(hiO, loO, 0x05010400u), addk);
  out.w = (int)pk_add16(__builtin_amdgcn_perm(hiO, loO, 0x07030602u), addk);
  return out;
}
__device__ __forceinline__ unsigned make_addk(int s) {
  int k = s - 127;
  unsigned t = ((unsigned)(k << 7)) & 0xFFFFu;
  return t | (t << 16);
}

// raw chunk (8 fp4 as int32-per-byte) + e8m0 scale -> bf16x8 fragment
__device__ __forceinline__ bf16x8 decode_frag(int4 raw, int s) {
#if USE_CVT
  unsigned t0 = __builtin_amdgcn_perm((unsigned)raw.y, (unsigned)raw.x, 0x00000400u);
  unsigned t1 = __builtin_amdgcn_perm((unsigned)raw.w, (unsigned)raw.z, 0x00000400u);
  unsigned p  = __builtin_amdgcn_perm(t1, t0, 0x05040100u);
  float scf = __uint_as_float((unsigned)s << 23);
  bf16x2 a = __builtin_amdgcn_cvt_scalef32_pk_bf16_fp4(p, scf, 0);
  bf16x2 b = __builtin_amdgcn_cvt_scalef32_pk_bf16_fp4(p, scf, 1);
  bf16x2 c = __builtin_amdgcn_cvt_scalef32_pk_bf16_fp4(p, scf, 2);
  bf16x2 d = __builtin_amdgcn_cvt_scalef32_pk_bf16_fp4(p, scf, 3);
  bf16x8 r;
  r[0]=a[0]; r[1]=a[1]; r[2]=b[0]; r[3]=b[1]; r[4]=c[0]; r[5]=c[1]; r[6]=d[0]; r[7]=d[1];
  return r;
#else
  int4 d4 = decode_chunk(raw, make_addk(s));
  bf16x8 r; __builtin_memcpy(&r, &d4, 16);
  return r;
#endif
}

__device__ __forceinline__ void gll16(const void* g, void* l) {
  __builtin_amdgcn_global_load_lds(
      (const __attribute__((address_space(1))) void*)g,
      (__attribute__((address_space(3))) void*)l, 16, 0, 0);
}

// bijective chunked XCD swizzle (m204)
__device__ __forceinline__ int xcd_swz(int wg, int nwg) {
  int q = nwg >> 3, r = nwg & 7;
  int xcd = wg & 7, pos = wg >> 3;
  return (xcd < r ? xcd * (q + 1) : r * (q + 1) + (xcd - r) * q) + pos;
}

// ---------------- fused prep + hs convert ----------------
__global__ __launch_bounds__(1024) void prep_convert(
    const float* __restrict__ logits, const int* __restrict__ dk, int T, int E,
    float* __restrict__ route, float* __restrict__ tw,
    int* __restrict__ lists, int* __restrict__ counts,
    int* __restrict__ tabGU, int* __restrict__ tabDN,
    const float* __restrict__ hs, __bf16* __restrict__ hsb, int n8) {
  if ((int)blockIdx.x < (int)gridDim.x - 1) {
    int g = blockIdx.x * 1024 + threadIdx.x;
    if (g < n8) {
      const float4* p = (const float4*)hs + (size_t)g * 2;
      float4 a = p[0], b = p[1];
      bf16x8 r;
#if USE_CVT
      r[0] = (__bf16)a.x; r[1] = (__bf16)a.y; r[2] = (__bf16)a.z; r[3] = (__bf16)a.w;
      r[4] = (__bf16)b.x; r[5] = (__bf16)b.y; r[6] = (__bf16)b.z; r[7] = (__bf16)b.w;
#else
      r[0] = (__bf16)a.x; r[1] = (__bf16)a.z; r[2] = (__bf16)b.x; r[3] = (__bf16)b.z;
      r[4] = (__bf16)a.y; r[5] = (__bf16)a.w; r[6] = (__bf16)b.y; r[7] = (__bf16)b.w;
#endif
      *(bf16x8*)(hsb + (size_t)g * 8) = r;
    }
    return;
  }
  __shared__ unsigned char s_ti[1024];
  __shared__ int s_cnt[EMAX];
  int t = threadIdx.x;
  int kk = *dk; if (kk > KMAX) kk = KMAX; if (kk < 1) kk = 1;
  int EE = E > EMAX ? EMAX : E;
  if (t < T) {
    float v[EMAX]; bool used[EMAX];
    for (int e = 0; e < EE; ++e) { v[e] = logits[t * E + e]; used[e] = false; route[t * E + e] = 0.f; }
    float tv[KMAX]; int ti[KMAX];
    for (int j = 0; j < kk; ++j) {
      float best = -3.4e38f; int bi = 0;
      for (int e = 0; e < EE; ++e) if (!used[e] && v[e] > best) { best = v[e]; bi = e; }
      used[bi] = true; tv[j] = best; ti[j] = bi;
    }
    float mx = tv[0], ssum = 0.f, wj[KMAX];
    for (int j = 0; j < kk; ++j) { wj[j] = __expf(tv[j] - mx); ssum += wj[j]; }
    for (int j = 0; j < kk; ++j) {
      float wv = wj[j] / ssum;
      route[t * E + ti[j]] = wv;
      tw[t * kk + j] = wv;
    }
    s_ti[t] = (unsigned char)(ti[0] | ((kk > 1 ? ti[1] : 0xF) << 4));
  } else if (t < 1024) {
    s_ti[t] = 0xFF;
  }
  __syncthreads();
  int w = t >> 6, lane = t & 63;
  if (w < EE) {
    int e = w, cnt = 0;
    for (int base = 0; base < T; base += 64) {
      int tt = base + lane;
      int j = -1;
      if (tt < T) {
        int packed = s_ti[tt];
        if ((packed & 0xF) == e) j = 0;
        else if ((packed >> 4) == e) j = 1;
      }
      unsigned long long m = __ballot(j >= 0);
      if (j >= 0) {
        int pre = __popcll(m & ((1ull << lane) - 1ull));
        lists[e * T + cnt + pre] = (tt << 3) | j;
      }
      cnt += __popcll(m);
    }
    if (lane == 0) { counts[e] = cnt; s_cnt[e] = cnt; }
  }
  __syncthreads();
  if (t == 0) {
    int g = 0, d = 0;
    for (int e = 0; e < EE; ++e) {
      int c = s_cnt[e];
      for (int m = 0; m * 128 < c && g < GU_TILES; ++m) tabGU[g++] = (e << 16) | m;
      for (int m = 0; m * 64 < c && d < DN_TILES; ++m) tabDN[d++] = (e << 16) | m;
    }
    for (; g < GU_TILES; ++g) tabGU[g] = -1;
    for (; d < DN_TILES; ++d) tabDN[d] = -1;
  }
}

// ================= gate+up GEMM: M=128 x N=128, 8 waves, depth-3 pipeline =================
// Wave w: wr=w>>2 (row half 64), wc=w&3 (col group 32). 4 gll16/batch/wave, vmcnt(8).
// Per-block K-rotation desynchronizes global bursts.
__global__ __launch_bounds__(512, 2) void gemm_gate_up(
    const __bf16* __restrict__ hsb,
    const int* __restrict__ gblk, const int* __restrict__ gscl, const float* __restrict__ gbias,
    const int* __restrict__ ublk, const int* __restrict__ uscl, const float* __restrict__ ubias,
    const int* __restrict__ lists, const int* __restrict__ counts,
    const float* __restrict__ tw, const int* __restrict__ dk,
    const int* __restrict__ tab,
    __bf16* __restrict__ act, int T)
{
  int lin = xcd_swz(blockIdx.x, GU_TILES * (II / 64));
  int ntile = lin / GU_TILES, xt = lin % GU_TILES;
  int te = tab[xt];
  if (te < 0) return;
  int e = te >> 16, mtile = te & 0xFFFF;
  int cnt = counts[e];
  int n_valid = cnt - mtile * 128;
  if (n_valid <= 0) return;
  if (n_valid > 128) n_valid = 128;
  int kk = *dk; if (kk > KMAX) kk = KMAX; if (kk < 1) kk = 1;
  int ibase = ntile * 64;
  int koff = (lin * 5) & 15;   // per-block K rotation

  __shared__ int s_tok[128];
  __shared__ __attribute__((aligned(16))) char Abuf[3][16384];  // 128 rows x 128B, [row][c^(row&7)]
  __shared__ __attribute__((aligned(16))) char Bbuf[3][16384];  // 128 rows raw fp4-inflated
  __shared__ __attribute__((aligned(8))) unsigned short sS[128][36];

  int tid = threadIdx.x;
  if (tid < 128) {
    int idx = mtile * 128 + tid;
    s_tok[tid] = lists[e * T + (idx < cnt ? idx : mtile * 128)];
  }
  __syncthreads();

  int lane = tid & 63, w = tid >> 6;     // 8 waves
  int wr = w >> 2, wc = w & 3;
  int l31 = lane & 31, kg2 = lane >> 5;
  int sub = lane >> 3, cL = lane & 7;
  int cA = cL ^ (sub & 7);

  // staging: wave w covers A rows [w*16, w*16+16) and B rows [w*16, w*16+16)
  const char* aSrc[2];
  #pragma unroll
  for (int q = 0; q < 2; ++q) {
    int row = w * 16 + q * 8 + sub;
    int tok = s_tok[row] >> 3;
    aSrc[q] = (const char*)hsb + (size_t)tok * (HH * 2) + (size_t)cA * 16;
  }
  const char* bSrc[2];
  #pragma unroll
  for (int q = 0; q < 2; ++q) {
    int row = w * 16 + q * 8 + sub;            // B row n: mat=(n>>4)&1, i=ibase+(n>>5)*16+(n&15)
    int mat = (row >> 4) & 1;
    int i = ibase + ((row >> 5) << 4) + (row & 15);
    const int* base = mat ? ublk : gblk;
    bSrc[q] = (const char*)(base + ((size_t)e * II + i) * (HH / 2)) + (size_t)cA * 16;
  }

  // scales: 128 rows x 8 int4-chunks = 1024 -> 2 per thread
  int4 sv4[2];
  #pragma unroll
  for (int rep = 0; rep < 2; ++rep) {
    int idx = tid + rep * 512;
    int row = idx >> 3, c4 = idx & 7;
    int mat = (row >> 4) & 1;
    int i = ibase + ((row >> 5) << 4) + (row & 15);
    const int* sbase = mat ? uscl : gscl;
    sv4[rep] = *((const int4*)(sbase + ((size_t)e * II + i) * 32) + c4);
  }
  asm volatile("s_waitcnt vmcnt(0)" ::: "memory");
  SCHED0();
  #pragma unroll
  for (int rep = 0; rep < 2; ++rep) {
    int idx = tid + rep * 512;
    int row = idx >> 3, c4 = idx & 7;
    unsigned short* dst = &sS[row][c4 * 4];
    dst[0] = (unsigned short)sv4[rep].x; dst[1] = (unsigned short)sv4[rep].y;
    dst[2] = (unsigned short)sv4[rep].z; dst[3] = (unsigned short)sv4[rep].w;
  }
  // issue pipeline batches 0,1,2 (4 gll16/wave each)
  #pragma unroll
  for (int b = 0; b < 3; ++b) {
    int ks = (b + koff) & 15;
    #pragma unroll
    for (int q = 0; q < 2; ++q) {
      gll16(aSrc[q] + ks * 128, Abuf[b] + (w * 16 + q * 8) * 128);
      gll16(bSrc[q] + ks * 128, Bbuf[b] + (w * 16 + q * 8) * 128);
    }
  }
  asm volatile("s_waitcnt vmcnt(8)" ::: "memory");     // batch0 landed
  asm volatile("s_waitcnt lgkmcnt(0)" ::: "memory");   // sS visible
  SCHED0();
  __builtin_amdgcn_s_barrier();
  SCHED0();

  f32x16 acc0 = (f32x16)0.f, acc1 = (f32x16)0.f;
  int brow = wc * 32 + l31;

  constexpr int NK = HH / 64;  // 16
  #pragma unroll 1
  for (int t = 0; t < NK; ++t) {
    int bi = t % 3;
    int ks = (t + koff) & 15;
    const char* Ac = Abuf[bi];
    const char* Bc = Bbuf[bi];
    unsigned sv = *(const unsigned*)((const char*)sS + brow * 72 + ks * 4);
    #pragma unroll
    for (int s = 0; s < 4; ++s) {
      int kc = kg2 + 2 * s;
      int4 rawb = *(const int4*)(Bc + brow * 128 + ((kc ^ (brow & 7)) << 4));
      bf16x8 bb = decode_frag(rawb, (s >> 1) ? (int)(sv >> 16) : (int)(sv & 0xFFFF));
      int m0 = wr * 64 + l31;
      bf16x8 a0 = *(const bf16x8*)(Ac + m0 * 128 + ((kc ^ (m0 & 7)) << 4));
      int m1 = m0 + 32;
      bf16x8 a1 = *(const bf16x8*)(Ac + m1 * 128 + ((kc ^ (m1 & 7)) << 4));
      acc0 = __builtin_amdgcn_mfma_f32_32x32x16_bf16(a0, bb, acc0, 0, 0, 0);
      acc1 = __builtin_amdgcn_mfma_f32_32x32x16_bf16(a1, bb, acc1, 0, 0, 0);
    }
    asm volatile("s_waitcnt lgkmcnt(0)" ::: "memory");
    SCHED0();
    __builtin_amdgcn_s_barrier();   // all waves done reading buf[bi]
    SCHED0();
    if (t + 3 < NK) {
      int ksn = (t + 3 + koff) & 15;
      #pragma unroll
      for (int q = 0; q < 2; ++q) {
        gll16(aSrc[q] + ksn * 128, Abuf[bi] + (w * 16 + q * 8) * 128);
        gll16(bSrc[q] + ksn * 128, Bbuf[bi] + (w * 16 + q * 8) * 128);
      }
      asm volatile("s_waitcnt vmcnt(8)" ::: "memory");   // batch t+1 landed
    } else if (t + 2 < NK) {
      asm volatile("s_waitcnt vmcnt(4)" ::: "memory");
    } else {
      asm volatile("s_waitcnt vmcnt(0)" ::: "memory");
    }
    SCHED0();
    __builtin_amdgcn_s_barrier();
    SCHED0();
  }

  // epilogue: col pairs (n, n^16) = (gate, up) of i = ibase + wc*16 + (l31&15)
  {
    bool isGate = (l31 & 16) == 0;
    int i_log = ibase + wc * 16 + (l31 & 15);
    float gb = gbias[e * II + i_log], ub = ubias[e * II + i_log];
#if USE_CVT
    int i_st = i_log;
#else
    int i_st = (i_log & ~7) | ((i_log & 1) << 2) | ((i_log & 7) >> 1);
#endif
    #pragma unroll
    for (int r = 0; r < 16; ++r) {
      float gv = acc0[r];
      float ov = __shfl_xor(gv, 16);
      int row = wr * 64 + (r & 3) + 8 * (r >> 2) + 4 * kg2;
      if (isGate && row < n_valid) {
        int entry = s_tok[row];
        int t2 = entry >> 3, j = entry & 7;
        float wv = tw[t2 * kk + j];
        float g = fminf(gv + gb, FLIMIT);
        float u = fminf(fmaxf(ov + ub, -FLIMIT), FLIMIT);
        float glu = g / (1.f + __expf(-FALPHA * g));
        act[((size_t)t2 * kk + j) * II + i_st] = (__bf16)((u + 1.f) * glu * wv);
      }
    }
    #pragma unroll
    for (int r = 0; r < 16; ++r) {
      float gv = acc1[r];
      float ov = __shfl_xor(gv, 16);
      int row = wr * 64 + (r & 3) + 8 * (r >> 2) + 4 * kg2 + 32;
      if (isGate && row < n_valid) {
        int entry = s_tok[row];
        int t2 = entry >> 3, j = entry & 7;
        float wv = tw[t2 * kk + j];
        float g = fminf(gv + gb, FLIMIT);
        float u = fminf(fmaxf(ov + ub, -FLIMIT), FLIMIT);
        float glu = g / (1.f + __expf(-FALPHA * g));
        act[((size_t)t2 * kk + j) * II + i_st] = (__bf16)((u + 1.f) * glu * wv);
      }
    }
  }
}

// ================= down GEMM: M=64 x N=128, 8 waves, depth-3 pipeline =================
__global__ __launch_bounds__(512, 2) void gemm_down(
    const __bf16* __restrict__ act,
    const int* __restrict__ dblk, const int* __restrict__ dscl,
    const int* __restrict__ lists, const int* __restrict__ counts,
    const int* __restrict__ dk, const int* __restrict__ tab,
    __bf16* __restrict__ partial, int T)
{
  int lin = xcd_swz(blockIdx.x, DN_TILES * (HH / 128));
  int ntile = lin / DN_TILES, xt = lin % DN_TILES;
  int te = tab[xt];
  if (te < 0) return;
  int e = te >> 16, mtile = te & 0xFFFF;
  int cnt = counts[e];
  int n_valid = cnt - mtile * 64;
  if (n_valid <= 0) return;
  if (n_valid > 64) n_valid = 64;
  int kk = *dk; if (kk > KMAX) kk = KMAX; if (kk < 1) kk = 1;
  int hbase = ntile * 128;
  int koff = (lin * 5) & 15;

  __shared__ int s_tok[64];
  __shared__ __attribute__((aligned(16))) char Abuf[3][8192];   // 64 rows
  __shared__ __attribute__((aligned(16))) char Bbuf[3][16384];  // 128 rows
  __shared__ __attribute__((aligned(8))) unsigned short sS[128][36];

  int tid = threadIdx.x;
  if (tid < 64) {
    int idx = mtile * 64 + tid;
    s_tok[tid] = lists[e * T + (idx < cnt ? idx : mtile * 64)];
  }
  __syncthreads();

  int lane = tid & 63, w = tid >> 6;
  int wr = w >> 2, wc = w & 3;
  int l31 = lane & 31, kg2 = lane >> 5;
  int sub = lane >> 3, cL = lane & 7;
  int cA = cL ^ (sub & 7);

  // staging: wave w covers A rows [w*8, w*8+8) (1 gll16) and B rows [w*16, w*16+16) (2 gll16)
  const char* aSrc0;
  {
    int row = w * 8 + sub;
    int entry = s_tok[row];
    size_t slot = (size_t)(entry >> 3) * kk + (entry & 7);
    aSrc0 = (const char*)act + slot * (II * 2) + (size_t)cA * 16;
  }
  const char* bSrc[2];
  #pragma unroll
  for (int q = 0; q < 2; ++q) {
    int row = w * 16 + q * 8 + sub;
    bSrc[q] = (const char*)(dblk + ((size_t)e * HH + hbase + row) * (II / 2)) + (size_t)cA * 16;
  }

  int4 sv4[2];
  #pragma unroll
  for (int rep = 0; rep < 2; ++rep) {
    int idx = tid + rep * 512;
    int row = idx >> 3, c4 = idx & 7;
    sv4[rep] = *((const int4*)(dscl + ((size_t)e * HH + hbase + row) * 32) + c4);
  }
  asm volatile("s_waitcnt vmcnt(0)" ::: "memory");
  SCHED0();
  #pragma unroll
  for (int rep = 0; rep < 2; ++rep) {
    int idx = tid + rep * 512;
    int row = idx >> 3, c4 = idx & 7;
    unsigned short* dst = &sS[row][c4 * 4];
    dst[0] = (unsigned short)sv4[rep].x; dst[1] = (unsigned short)sv4[rep].y;
    dst[2] = (unsigned short)sv4[rep].z; dst[3] = (unsigned short)sv4[rep].w;
  }
  #pragma unroll
  for (int b = 0; b < 3; ++b) {
    int ks = (b + koff) & 15;
    gll16(aSrc0 + ks * 128, Abuf[b] + (w * 8) * 128);
    #pragma unroll
    for (int q = 0; q < 2; ++q)
      gll16(bSrc[q] + ks * 128, Bbuf[b] + (w * 16 + q * 8) * 128);
  }
  asm volatile("s_waitcnt vmcnt(6)" ::: "memory");
  asm volatile("s_waitcnt lgkmcnt(0)" ::: "memory");
  SCHED0();
  __builtin_amdgcn_s_barrier();
  SCHED0();

  f32x16 acc0 = (f32x16)0.f;
  int brow = wc * 32 + l31;
  int m0 = wr * 32 + l31;

  constexpr int NK = II / 64;  // 16
  #pragma unroll 1
  for (int t = 0; t < NK; ++t) {
    int bi = t % 3;
    int ks = (t + koff) & 15;
    const char* Ac = Abuf[bi];
    const char* Bc = Bbuf[bi];
    unsigned sv = *(const unsigned*)((const char*)sS + brow * 72 + ks * 4);
    #pragma unroll
    for (int s = 0; s < 4; ++s) {
      int kc = kg2 + 2 * s;
      int4 rawb = *(const int4*)(Bc + brow * 128 + ((kc ^ (brow & 7)) << 4));
      bf16x8 bb = decode_frag(rawb, (s >> 1) ? (int)(sv >> 16) : (int)(sv & 0xFFFF));
      bf16x8 a0 = *(const bf16x8*)(Ac + m0 * 128 + ((kc ^ (m0 & 7)) << 4));
      acc0 = __builtin_amdgcn_mfma_f32_32x32x16_bf16(a0, bb, acc0, 0, 0, 0);
    }
    asm volatile("s_waitcnt lgkmcnt(0)" ::: "memory");
    SCHED0();
    __builtin_amdgcn_s_barrier();
    SCHED0();
    if (t + 3 < NK) {
      int ksn = (t + 3 + koff) & 15;
      gll16(aSrc0 + ksn * 128, Abuf[bi] + (w * 8) * 128);
      #pragma unroll
      for (int q = 0; q < 2; ++q)
        gll16(bSrc[q] + ksn * 128, Bbuf[bi] + (w * 16 + q * 8) * 128);
      asm volatile("s_waitcnt vmcnt(6)" ::: "memory");
    } else if (t + 2 < NK) {
      asm volatile("s_waitcnt vmcnt(3)" ::: "memory");
    } else {
      asm volatile("s_waitcnt vmcnt(0)" ::: "memory");
    }
    SCHED0();
    __builtin_amdgcn_s_barrier();
    SCHED0();
  }

  // epilogue: h = hbase + wc*32 + l31; rows = wr*32 + crow
  {
    int h = hbase + wc * 32 + l31;
    #pragma unroll
    for (int r = 0; r < 16; ++r) {
      int row = wr * 32 + (r & 3) + 8 * (r >> 2) + 4 * kg2;
      if (row < n_valid) {
        int entry = s_tok[row];
        int t2 = entry >> 3, j = entry & 7;
        partial[((size_t)t2 * kk + j) * HH + h] = (__bf16)acc0[r];
      }
    }
  }
}

// ---------------- combine ----------------
__global__ void combine_kernel(const __bf16* __restrict__ partial, const float* __restrict__ route,
                               const float* __restrict__ dbias, const int* __restrict__ dk,
                               float* __restrict__ out, int E) {
  int t = blockIdx.y;
  int h = blockIdx.x * 256 + threadIdx.x;
  int kk = *dk; if (kk > KMAX) kk = KMAX; if (kk < 1) kk = 1;
  float s = 0.f;
  for (int j = 0; j < kk; ++j) s += (float)partial[((size_t)t * kk + j) * HH + h];
  for (int e = 0; e < E; ++e) s += route[t * E + e] * dbias[(size_t)e * HH + h];
  out[(size_t)t * HH + h] = s;
}

extern "C" void kernel_launch(void* const* d_in, const int* in_sizes, int n_in,
                              void* d_out, int out_size, void* d_ws, size_t ws_size,
                              hipStream_t stream) {
  const float* hs    = (const float*)d_in[0];
  const float* rl    = (const float*)d_in[1];
  const int*   gblk  = (const int*)d_in[2];
  const int*   gscl  = (const int*)d_in[3];
  const float* gbias = (const float*)d_in[4];
  const int*   ublk  = (const int*)d_in[5];
  const int*   uscl  = (const int*)d_in[6];
  const float* ubias = (const float*)d_in[7];
  const int*   dblk  = (const int*)d_in[8];
  const int*   dscl  = (const int*)d_in[9];
  const float* dbias = (const float*)d_in[10];
  const int*   dk    = (const int*)d_in[11];

  long s0 = in_sizes[0], s1 = in_sizes[1], s2 = in_sizes[2], s4 = in_sizes[4];
  int H = (int)(2 * s2 / s4);       // = 1024
  int T = (int)(s0 / H);            // = 1024
  int E = (int)(s1 / T);            // = 8

  char* w = (char*)d_ws;
  auto alloc = [&](size_t bytes) { char* p = w; w += (bytes + 255) & ~size_t(255); return p; };
  float*  route   = (float*)alloc(sizeof(float) * (size_t)T * E);
  float*  twp     = (float*)alloc(sizeof(float) * (size_t)T * KMAX);
  int*    counts  = (int*)  alloc(sizeof(int)   * (size_t)E);
  int*    lists   = (int*)  alloc(sizeof(int)   * (size_t)E * T);
  int*    tabGU   = (int*)  alloc(sizeof(int)   * GU_TILES);
  int*    tabDN   = (int*)  alloc(sizeof(int)   * DN_TILES);
  __bf16* hsb     = (__bf16*)alloc(sizeof(__bf16) * (size_t)T * HH);
  __bf16* act     = (__bf16*)alloc(sizeof(__bf16) * (size_t)T * KMAX * II);
  __bf16* partial = (__bf16*)alloc(sizeof(__bf16) * (size_t)T * KMAX * HH);

  int n8 = T * HH / 8;
  int nConv = (n8 + 1023) / 1024;
  prep_convert<<<dim3(nConv + 1), 1024, 0, stream>>>(
      rl, dk, T, E, route, twp, lists, counts, tabGU, tabDN, hs, hsb, n8);
  gemm_gate_up<<<dim3(GU_TILES * (II / 64)), 512, 0, stream>>>(
      hsb, gblk, gscl, gbias, ublk, uscl, ubias, lists, counts, twp, dk, tabGU, act, T);
  gemm_down<<<dim3(DN_TILES * (HH / 128)), 512, 0, stream>>>(
      act, dblk, dscl, lists, counts, dk, tabDN, partial, T);
  combine_kernel<<<dim3(HH / 256, T), 256, 0, stream>>>(partial, route, dbias, dk, (float*)d_out, E);
}